// Round 1
// baseline (9512.651 us; speedup 1.0000x reference)
//
#include <hip/hip_runtime.h>
#include <hip/hip_bf16.h>
#include <math.h>

#define N_NODES 100000
#define N_EDGES 3200000
#define F_INDIM 512
#define C_DIM 64
#define K_ITERS 50
#define ALPHA_F 0.1f

// ---------------------------------------------------------------------------
// CSR build
// ---------------------------------------------------------------------------
__global__ void init_deg_kernel(int* __restrict__ deg, int* __restrict__ cursor) {
    int i = blockIdx.x * 256 + threadIdx.x;
    if (i < N_NODES) { deg[i] = 1; cursor[i] = 0; }  // 1 = self loop
}

__global__ void count_deg_kernel(const int* __restrict__ dst, int* __restrict__ deg) {
    int e = blockIdx.x * 256 + threadIdx.x;
    if (e < N_EDGES) atomicAdd(&deg[dst[e]], 1);
}

__global__ void dinv_kernel(const int* __restrict__ deg, float* __restrict__ dinv) {
    int i = blockIdx.x * 256 + threadIdx.x;
    if (i < N_NODES) dinv[i] = rsqrtf((float)deg[i]);
}

// exclusive scan of deg -> row_ptr, 256 elems per block
__global__ void scan_block_kernel(const int* __restrict__ deg, int* __restrict__ row_ptr,
                                  int* __restrict__ blksum) {
    __shared__ int tmp[256];
    int i = blockIdx.x * 256 + threadIdx.x;
    int v = (i < N_NODES) ? deg[i] : 0;
    tmp[threadIdx.x] = v;
    __syncthreads();
    for (int o = 1; o < 256; o <<= 1) {
        int t = (threadIdx.x >= o) ? tmp[threadIdx.x - o] : 0;
        __syncthreads();
        tmp[threadIdx.x] += t;
        __syncthreads();
    }
    if (i < N_NODES) row_ptr[i] = tmp[threadIdx.x] - v;   // exclusive within block
    if (threadIdx.x == 255) blksum[blockIdx.x] = tmp[255];
}

__global__ void scan_top_kernel(int* __restrict__ blksum, int nb) {
    __shared__ int tmp[512];
    int v = (threadIdx.x < nb) ? blksum[threadIdx.x] : 0;
    tmp[threadIdx.x] = v;
    __syncthreads();
    for (int o = 1; o < 512; o <<= 1) {
        int t = (threadIdx.x >= o) ? tmp[threadIdx.x - o] : 0;
        __syncthreads();
        tmp[threadIdx.x] += t;
        __syncthreads();
    }
    if (threadIdx.x < nb) blksum[threadIdx.x] = tmp[threadIdx.x] - v;  // exclusive
}

__global__ void scan_add_kernel(int* __restrict__ row_ptr, const int* __restrict__ blksum) {
    int i = blockIdx.x * 256 + threadIdx.x;
    if (i < N_NODES) row_ptr[i] += blksum[blockIdx.x];
    if (i == 0) row_ptr[N_NODES] = N_EDGES + N_NODES;
}

__global__ void scatter_kernel(const int* __restrict__ src, const int* __restrict__ dst,
                               const float* __restrict__ dinv, const int* __restrict__ row_ptr,
                               int* __restrict__ cursor, int* __restrict__ cols,
                               float* __restrict__ vals) {
    int e = blockIdx.x * 256 + threadIdx.x;
    if (e < N_EDGES) {
        int s = src[e], d = dst[e];
        int pos = atomicAdd(&cursor[d], 1);
        int idx = row_ptr[d] + pos;
        cols[idx] = s;
        vals[idx] = dinv[s] * dinv[d];
    } else if (e < N_EDGES + N_NODES) {
        int i = e - N_EDGES;
        int pos = atomicAdd(&cursor[i], 1);
        int idx = row_ptr[i] + pos;
        cols[idx] = i;
        float di = dinv[i];
        vals[idx] = di * di;
    }
}

// ---------------------------------------------------------------------------
// GEMM: h0 = relu(x @ W + b)   [100000 x 512] @ [512 x 64]
// 256 threads: c = tid&63 (output col), rq = tid>>6; each thread does 8 rows.
// 32 rows per block, W staged in LDS in 128-row chunks (32 KB).
// ---------------------------------------------------------------------------
__global__ __launch_bounds__(256) void gemm_relu_kernel(const float* __restrict__ x,
                                                        const float* __restrict__ W,
                                                        const float* __restrict__ b,
                                                        float* __restrict__ h0) {
    __shared__ float Wt[128 * 64];
    const int tid = threadIdx.x;
    const int c = tid & 63;
    const int rq = tid >> 6;               // 0..3
    const int row0 = blockIdx.x * 32 + rq * 8;

    float acc[8];
#pragma unroll
    for (int k = 0; k < 8; k++) acc[k] = 0.f;

    for (int ch = 0; ch < 4; ch++) {
        __syncthreads();
#pragma unroll
        for (int i = tid; i < 8192; i += 256) Wt[i] = W[ch * 8192 + i];
        __syncthreads();
#pragma unroll 2
        for (int f4 = 0; f4 < 32; f4++) {
            float w0 = Wt[(f4 * 4 + 0) * 64 + c];
            float w1 = Wt[(f4 * 4 + 1) * 64 + c];
            float w2 = Wt[(f4 * 4 + 2) * 64 + c];
            float w3 = Wt[(f4 * 4 + 3) * 64 + c];
#pragma unroll
            for (int k = 0; k < 8; k++) {
                const float4 xv = *reinterpret_cast<const float4*>(
                    &x[(size_t)(row0 + k) * F_INDIM + ch * 128 + f4 * 4]);
                acc[k] = fmaf(xv.x, w0, acc[k]);
                acc[k] = fmaf(xv.y, w1, acc[k]);
                acc[k] = fmaf(xv.z, w2, acc[k]);
                acc[k] = fmaf(xv.w, w3, acc[k]);
            }
        }
    }
    float bb = b[c];
#pragma unroll
    for (int k = 0; k < 8; k++) {
        float v = acc[k] + bb;
        h0[(size_t)(row0 + k) * C_DIM + c] = v > 0.f ? v : 0.f;
    }
}

// ---------------------------------------------------------------------------
// One propagation step: hn = 0.9 * (A_hat @ hp) + 0.1 * x0
// One wave per node; lane = channel. Gather of hp is 256B fully coalesced.
// ---------------------------------------------------------------------------
__global__ __launch_bounds__(256) void spmm_step_kernel(const int* __restrict__ row_ptr,
                                                        const int* __restrict__ cols,
                                                        const float* __restrict__ vals,
                                                        const float* __restrict__ hp,
                                                        const float* __restrict__ x0,
                                                        float* __restrict__ hn) {
    int node = blockIdx.x * 4 + (threadIdx.x >> 6);
    if (node >= N_NODES) return;
    int c = threadIdx.x & 63;
    int s = row_ptr[node];
    int e = row_ptr[node + 1];
    float acc = 0.f;
    int j = s;
    for (; j + 1 < e; j += 2) {
        int c0 = cols[j];
        int c1 = cols[j + 1];
        float v0 = vals[j];
        float v1 = vals[j + 1];
        acc = fmaf(v0, hp[(size_t)c0 * C_DIM + c], acc);
        acc = fmaf(v1, hp[(size_t)c1 * C_DIM + c], acc);
    }
    if (j < e) acc = fmaf(vals[j], hp[(size_t)cols[j] * C_DIM + c], acc);
    size_t oi = (size_t)node * C_DIM + c;
    hn[oi] = (1.0f - ALPHA_F) * acc + ALPHA_F * x0[oi];
}

// ---------------------------------------------------------------------------
// log_softmax over the 64 channels (one wave per node)
// ---------------------------------------------------------------------------
__global__ __launch_bounds__(256) void logsoftmax_kernel(const float* __restrict__ h,
                                                         float* __restrict__ out) {
    int node = blockIdx.x * 4 + (threadIdx.x >> 6);
    if (node >= N_NODES) return;
    int c = threadIdx.x & 63;
    float v = h[(size_t)node * C_DIM + c];
    float m = v;
#pragma unroll
    for (int o = 32; o > 0; o >>= 1) m = fmaxf(m, __shfl_xor(m, o));
    float ex = expf(v - m);
    float sum = ex;
#pragma unroll
    for (int o = 32; o > 0; o >>= 1) sum += __shfl_xor(sum, o);
    out[(size_t)node * C_DIM + c] = (v - m) - logf(sum);
}

// ---------------------------------------------------------------------------
extern "C" void kernel_launch(void* const* d_in, const int* in_sizes, int n_in,
                              void* d_out, int out_size, void* d_ws, size_t ws_size,
                              hipStream_t stream) {
    const float* x   = (const float*)d_in[0];
    const int* ei    = (const int*)d_in[1];     // [2, E]
    const float* W   = (const float*)d_in[2];
    const float* b   = (const float*)d_in[3];
    const int* src = ei;
    const int* dst = ei + N_EDGES;
    float* out = (float*)d_out;

    // workspace layout
    char* ws = (char*)d_ws;
    size_t off = 0;
    auto alloc = [&](size_t bytes) -> void* {
        void* p = ws + off;
        off = (off + bytes + 255) & ~(size_t)255;
        return p;
    };
    int*   deg     = (int*)alloc(sizeof(int) * N_NODES);
    int*   cursor  = (int*)alloc(sizeof(int) * N_NODES);
    float* dinv    = (float*)alloc(sizeof(float) * N_NODES);
    int*   row_ptr = (int*)alloc(sizeof(int) * (N_NODES + 1));
    int*   blksum  = (int*)alloc(sizeof(int) * 1024);
    int*   cols    = (int*)alloc(sizeof(int) * (N_EDGES + N_NODES));
    float* vals    = (float*)alloc(sizeof(float) * (N_EDGES + N_NODES));
    float* x0h     = (float*)alloc(sizeof(float) * (size_t)N_NODES * C_DIM);
    float* hA      = (float*)alloc(sizeof(float) * (size_t)N_NODES * C_DIM);
    float* hB      = (float*)alloc(sizeof(float) * (size_t)N_NODES * C_DIM);
    (void)ws_size;

    const int NB_N   = (N_NODES + 255) / 256;                 // 391
    const int NB_E   = (N_EDGES + 255) / 256;                 // 12500
    const int NB_EN  = (N_EDGES + N_NODES + 255) / 256;       // 12891
    const int NB_NODE4 = (N_NODES + 3) / 4;                   // 25000

    // CSR build
    init_deg_kernel<<<NB_N, 256, 0, stream>>>(deg, cursor);
    count_deg_kernel<<<NB_E, 256, 0, stream>>>(dst, deg);
    dinv_kernel<<<NB_N, 256, 0, stream>>>(deg, dinv);
    scan_block_kernel<<<NB_N, 256, 0, stream>>>(deg, row_ptr, blksum);
    scan_top_kernel<<<1, 512, 0, stream>>>(blksum, NB_N);
    scan_add_kernel<<<NB_N, 256, 0, stream>>>(row_ptr, blksum);
    scatter_kernel<<<NB_EN, 256, 0, stream>>>(src, dst, dinv, row_ptr, cursor, cols, vals);

    // h0 = relu(x @ W + b)
    gemm_relu_kernel<<<N_NODES / 32, 256, 0, stream>>>(x, W, b, x0h);

    // K propagation steps, ping-pong
    const float* cur = x0h;
    float* bufs[2] = {hA, hB};
    for (int it = 0; it < K_ITERS; it++) {
        float* nxt = bufs[it & 1];
        spmm_step_kernel<<<NB_NODE4, 256, 0, stream>>>(row_ptr, cols, vals, cur, x0h, nxt);
        cur = nxt;
    }

    logsoftmax_kernel<<<NB_NODE4, 256, 0, stream>>>(cur, out);
}

// Round 2
// 3316.459 us; speedup vs baseline: 2.8683x; 2.8683x over previous
//
#include <hip/hip_runtime.h>
#include <hip/hip_fp16.h>
#include <math.h>

#define N_NODES 100000
#define N_EDGES 3200000
#define F_INDIM 512
#define C_DIM 64
#define K_ITERS 50
#define ALPHA_F 0.1f

// ---------------------------------------------------------------------------
// CSR build
// ---------------------------------------------------------------------------
__global__ void init_deg_kernel(int* __restrict__ deg, int* __restrict__ cursor) {
    int i = blockIdx.x * 256 + threadIdx.x;
    if (i < N_NODES) { deg[i] = 1; cursor[i] = 0; }  // 1 = self loop
}

__global__ void count_deg_kernel(const int* __restrict__ dst, int* __restrict__ deg) {
    int e = blockIdx.x * 256 + threadIdx.x;
    if (e < N_EDGES) atomicAdd(&deg[dst[e]], 1);
}

__global__ void dinv_kernel(const int* __restrict__ deg, float* __restrict__ dinv) {
    int i = blockIdx.x * 256 + threadIdx.x;
    if (i < N_NODES) dinv[i] = rsqrtf((float)deg[i]);
}

__global__ void scan_block_kernel(const int* __restrict__ deg, int* __restrict__ row_ptr,
                                  int* __restrict__ blksum) {
    __shared__ int tmp[256];
    int i = blockIdx.x * 256 + threadIdx.x;
    int v = (i < N_NODES) ? deg[i] : 0;
    tmp[threadIdx.x] = v;
    __syncthreads();
    for (int o = 1; o < 256; o <<= 1) {
        int t = (threadIdx.x >= o) ? tmp[threadIdx.x - o] : 0;
        __syncthreads();
        tmp[threadIdx.x] += t;
        __syncthreads();
    }
    if (i < N_NODES) row_ptr[i] = tmp[threadIdx.x] - v;
    if (threadIdx.x == 255) blksum[blockIdx.x] = tmp[255];
}

__global__ void scan_top_kernel(int* __restrict__ blksum, int nb) {
    __shared__ int tmp[512];
    int v = (threadIdx.x < nb) ? blksum[threadIdx.x] : 0;
    tmp[threadIdx.x] = v;
    __syncthreads();
    for (int o = 1; o < 512; o <<= 1) {
        int t = (threadIdx.x >= o) ? tmp[threadIdx.x - o] : 0;
        __syncthreads();
        tmp[threadIdx.x] += t;
        __syncthreads();
    }
    if (threadIdx.x < nb) blksum[threadIdx.x] = tmp[threadIdx.x] - v;
}

__global__ void scan_add_kernel(int* __restrict__ row_ptr, const int* __restrict__ blksum) {
    int i = blockIdx.x * 256 + threadIdx.x;
    if (i < N_NODES) row_ptr[i] += blksum[blockIdx.x];
    if (i == 0) row_ptr[N_NODES] = N_EDGES + N_NODES;
}

__global__ void scatter_kernel(const int* __restrict__ src, const int* __restrict__ dst,
                               const float* __restrict__ dinv, const int* __restrict__ row_ptr,
                               int* __restrict__ cursor, int2* __restrict__ pairs) {
    int e = blockIdx.x * 256 + threadIdx.x;
    if (e < N_EDGES) {
        int s = src[e], d = dst[e];
        int pos = atomicAdd(&cursor[d], 1);
        pairs[row_ptr[d] + pos] = make_int2(s, __float_as_int(dinv[s] * dinv[d]));
    } else if (e < N_EDGES + N_NODES) {
        int i = e - N_EDGES;
        int pos = atomicAdd(&cursor[i], 1);
        float di = dinv[i];
        pairs[row_ptr[i] + pos] = make_int2(i, __float_as_int(di * di));
    }
}

// ---------------------------------------------------------------------------
// GEMM: h0 = relu(x @ W + b)  -> x0f (fp32) and h0h (fp16)
// 128 rows x 64 cols per block, 256 threads, 4x8 register blocking,
// K chunked by 32 with LDS staging (coalesced global loads).
// ---------------------------------------------------------------------------
__global__ __launch_bounds__(256) void gemm_relu_kernel(const float* __restrict__ x,
                                                        const float* __restrict__ W,
                                                        const float* __restrict__ b,
                                                        float* __restrict__ x0f,
                                                        __half* __restrict__ h0h) {
    __shared__ float xs[128][36];   // +4 pad for bank spread
    __shared__ float ws[32][64];
    const int tid = threadIdx.x;
    const int c0 = (tid & 7) * 8;        // 8 output cols
    const int r0 = (tid >> 3) * 4;       // 4 output rows
    const int row0 = blockIdx.x * 128;

    float acc[4][8];
#pragma unroll
    for (int j = 0; j < 4; j++)
#pragma unroll
        for (int i = 0; i < 8; i++) acc[j][i] = 0.f;

    for (int kc = 0; kc < 16; kc++) {
        const int k0 = kc * 32;
        __syncthreads();
        // stage x tile: 128 rows x 32 k, 8 lanes per row (128B segments)
#pragma unroll
        for (int p = 0; p < 4; p++) {
            int lr = p * 32 + (tid >> 3);
            int gr = row0 + lr;
            if (gr >= N_NODES) gr = N_NODES - 1;
            float4 v = *reinterpret_cast<const float4*>(
                &x[(size_t)gr * F_INDIM + k0 + (tid & 7) * 4]);
            *reinterpret_cast<float4*>(&xs[lr][(tid & 7) * 4]) = v;
        }
        // stage W chunk: 32 x 64
#pragma unroll
        for (int p = 0; p < 2; p++) {
            int fi = p * 256 + tid;   // float4 index; row = fi>>4, col4 = fi&15
            float4 v = *reinterpret_cast<const float4*>(
                &W[(size_t)(k0 + (fi >> 4)) * C_DIM + (fi & 15) * 4]);
            *reinterpret_cast<float4*>(&ws[fi >> 4][(fi & 15) * 4]) = v;
        }
        __syncthreads();
#pragma unroll
        for (int k = 0; k < 32; k++) {
            float4 w0 = *reinterpret_cast<const float4*>(&ws[k][c0]);
            float4 w1 = *reinterpret_cast<const float4*>(&ws[k][c0 + 4]);
            float wr[8] = {w0.x, w0.y, w0.z, w0.w, w1.x, w1.y, w1.z, w1.w};
#pragma unroll
            for (int j = 0; j < 4; j++) {
                float xv = xs[r0 + j][k];
#pragma unroll
                for (int i = 0; i < 8; i++) acc[j][i] = fmaf(xv, wr[i], acc[j][i]);
            }
        }
    }

    const float4 b0 = *reinterpret_cast<const float4*>(&b[c0]);
    const float4 b1 = *reinterpret_cast<const float4*>(&b[c0 + 4]);
    float bb[8] = {b0.x, b0.y, b0.z, b0.w, b1.x, b1.y, b1.z, b1.w};
#pragma unroll
    for (int j = 0; j < 4; j++) {
        int gr = row0 + r0 + j;
        if (gr < N_NODES) {
            float o[8];
#pragma unroll
            for (int i = 0; i < 8; i++) {
                float v = acc[j][i] + bb[i];
                o[i] = v > 0.f ? v : 0.f;
            }
            float4 s0 = {o[0], o[1], o[2], o[3]};
            float4 s1 = {o[4], o[5], o[6], o[7]};
            *reinterpret_cast<float4*>(&x0f[(size_t)gr * C_DIM + c0]) = s0;
            *reinterpret_cast<float4*>(&x0f[(size_t)gr * C_DIM + c0 + 4]) = s1;
            union { float4 f; __half2 h[4]; } hw;
            hw.h[0] = __floats2half2_rn(o[0], o[1]);
            hw.h[1] = __floats2half2_rn(o[2], o[3]);
            hw.h[2] = __floats2half2_rn(o[4], o[5]);
            hw.h[3] = __floats2half2_rn(o[6], o[7]);
            *reinterpret_cast<float4*>(h0h + (size_t)gr * C_DIM + c0) = hw.f;
        }
    }
}

// ---------------------------------------------------------------------------
// One propagation step: hn = 0.9 * (A_hat @ hp) + 0.1 * x0   (hp/hn fp16)
// One wave per node; lane = (edge_sub 0..7, chan_grp 0..7); each lane gathers
// 16B (8 fp16 channels) for its edge. 16 edges per loop iteration, pair
// prefetch one iteration ahead.
// ---------------------------------------------------------------------------
__device__ __forceinline__ void acc_fma8(float acc[8], float v, float4 g) {
    union { float f; __half2 h; } u;
    u.f = g.x; float2 f0 = __half22float2(u.h);
    acc[0] = fmaf(v, f0.x, acc[0]); acc[1] = fmaf(v, f0.y, acc[1]);
    u.f = g.y; float2 f1 = __half22float2(u.h);
    acc[2] = fmaf(v, f1.x, acc[2]); acc[3] = fmaf(v, f1.y, acc[3]);
    u.f = g.z; float2 f2 = __half22float2(u.h);
    acc[4] = fmaf(v, f2.x, acc[4]); acc[5] = fmaf(v, f2.y, acc[5]);
    u.f = g.w; float2 f3 = __half22float2(u.h);
    acc[6] = fmaf(v, f3.x, acc[6]); acc[7] = fmaf(v, f3.y, acc[7]);
}

__global__ __launch_bounds__(256) void spmm_step_kernel(const int* __restrict__ rp,
                                                        const int2* __restrict__ pairs,
                                                        const __half* __restrict__ hp,
                                                        const float* __restrict__ x0,
                                                        __half* __restrict__ hn) {
    int node = blockIdx.x * 4 + (threadIdx.x >> 6);
    if (node >= N_NODES) return;
    int lane = threadIdx.x & 63;
    int esub = lane >> 3;            // which edge in the group of 8
    int cbase = (lane & 7) * 8;      // 8 fp16 channels per lane

    int s = rp[node];
    int e = rp[node + 1];

    float acc[8] = {0.f, 0.f, 0.f, 0.f, 0.f, 0.f, 0.f, 0.f};

    int j0 = s + esub;
    int2 pA = make_int2(0, 0), pB = make_int2(0, 0);
    if (j0 < e) pA = pairs[j0];
    if (j0 + 8 < e) pB = pairs[j0 + 8];

    for (int t = s; t < e; t += 16) {
        // prefetch next iteration's pairs
        int jn = t + 16 + esub;
        int2 nA = make_int2(0, 0), nB = make_int2(0, 0);
        if (jn < e) nA = pairs[jn];
        if (jn + 8 < e) nB = pairs[jn + 8];
        // gathers (col 0 when inactive -> safe, val = 0)
        float4 gA = *reinterpret_cast<const float4*>(hp + (size_t)pA.x * C_DIM + cbase);
        float4 gB = *reinterpret_cast<const float4*>(hp + (size_t)pB.x * C_DIM + cbase);
        acc_fma8(acc, __int_as_float(pA.y), gA);
        acc_fma8(acc, __int_as_float(pB.y), gB);
        pA = nA; pB = nB;
    }

    // reduce across the 8 edge_sub groups
#pragma unroll
    for (int off = 8; off <= 32; off <<= 1) {
#pragma unroll
        for (int i = 0; i < 8; i++) acc[i] += __shfl_xor(acc[i], off);
    }

    if (esub == 0) {
        size_t base = (size_t)node * C_DIM + cbase;
        float4 xa = *reinterpret_cast<const float4*>(x0 + base);
        float4 xb = *reinterpret_cast<const float4*>(x0 + base + 4);
        float xr[8] = {xa.x, xa.y, xa.z, xa.w, xb.x, xb.y, xb.z, xb.w};
        float o[8];
#pragma unroll
        for (int i = 0; i < 8; i++) o[i] = (1.0f - ALPHA_F) * acc[i] + ALPHA_F * xr[i];
        union { float4 f; __half2 h[4]; } hw;
        hw.h[0] = __floats2half2_rn(o[0], o[1]);
        hw.h[1] = __floats2half2_rn(o[2], o[3]);
        hw.h[2] = __floats2half2_rn(o[4], o[5]);
        hw.h[3] = __floats2half2_rn(o[6], o[7]);
        *reinterpret_cast<float4*>(hn + base) = hw.f;
    }
}

// ---------------------------------------------------------------------------
// log_softmax over 64 channels (one wave per node), fp16 in -> fp32 out
// ---------------------------------------------------------------------------
__global__ __launch_bounds__(256) void logsoftmax_kernel(const __half* __restrict__ h,
                                                         float* __restrict__ out) {
    int node = blockIdx.x * 4 + (threadIdx.x >> 6);
    if (node >= N_NODES) return;
    int c = threadIdx.x & 63;
    float v = __half2float(h[(size_t)node * C_DIM + c]);
    float m = v;
#pragma unroll
    for (int o = 32; o > 0; o >>= 1) m = fmaxf(m, __shfl_xor(m, o));
    float ex = expf(v - m);
    float sum = ex;
#pragma unroll
    for (int o = 32; o > 0; o >>= 1) sum += __shfl_xor(sum, o);
    out[(size_t)node * C_DIM + c] = (v - m) - logf(sum);
}

// ---------------------------------------------------------------------------
extern "C" void kernel_launch(void* const* d_in, const int* in_sizes, int n_in,
                              void* d_out, int out_size, void* d_ws, size_t ws_size,
                              hipStream_t stream) {
    const float* x = (const float*)d_in[0];
    const int* ei  = (const int*)d_in[1];   // [2, E]
    const float* W = (const float*)d_in[2];
    const float* b = (const float*)d_in[3];
    const int* src = ei;
    const int* dst = ei + N_EDGES;
    float* out = (float*)d_out;

    char* ws = (char*)d_ws;
    size_t off = 0;
    auto alloc = [&](size_t bytes) -> void* {
        void* p = ws + off;
        off = (off + bytes + 255) & ~(size_t)255;
        return p;
    };
    int*    deg     = (int*)alloc(sizeof(int) * N_NODES);
    int*    cursor  = (int*)alloc(sizeof(int) * N_NODES);
    float*  dinv    = (float*)alloc(sizeof(float) * N_NODES);
    int*    row_ptr = (int*)alloc(sizeof(int) * (N_NODES + 1));
    int*    blksum  = (int*)alloc(sizeof(int) * 1024);
    int2*   pairs   = (int2*)alloc(sizeof(int2) * (N_EDGES + N_NODES));
    float*  x0f     = (float*)alloc(sizeof(float) * (size_t)N_NODES * C_DIM);
    __half* h0h     = (__half*)alloc(sizeof(__half) * (size_t)N_NODES * C_DIM);
    __half* hA      = (__half*)alloc(sizeof(__half) * (size_t)N_NODES * C_DIM);
    __half* hB      = (__half*)alloc(sizeof(__half) * (size_t)N_NODES * C_DIM);
    (void)ws_size;

    const int NB_N  = (N_NODES + 255) / 256;
    const int NB_E  = (N_EDGES + 255) / 256;
    const int NB_EN = (N_EDGES + N_NODES + 255) / 256;
    const int NB_NODE4 = (N_NODES + 3) / 4;

    init_deg_kernel<<<NB_N, 256, 0, stream>>>(deg, cursor);
    count_deg_kernel<<<NB_E, 256, 0, stream>>>(dst, deg);
    dinv_kernel<<<NB_N, 256, 0, stream>>>(deg, dinv);
    scan_block_kernel<<<NB_N, 256, 0, stream>>>(deg, row_ptr, blksum);
    scan_top_kernel<<<1, 512, 0, stream>>>(blksum, NB_N);
    scan_add_kernel<<<NB_N, 256, 0, stream>>>(row_ptr, blksum);
    scatter_kernel<<<NB_EN, 256, 0, stream>>>(src, dst, dinv, row_ptr, cursor, pairs);

    gemm_relu_kernel<<<(N_NODES + 127) / 128, 256, 0, stream>>>(x, W, b, x0f, h0h);

    const __half* cur = h0h;
    __half* bufs[2] = {hA, hB};
    for (int it = 0; it < K_ITERS; it++) {
        __half* nxt = bufs[it & 1];
        spmm_step_kernel<<<NB_NODE4, 256, 0, stream>>>(row_ptr, pairs, cur, x0f, nxt);
        cur = nxt;
    }

    logsoftmax_kernel<<<NB_NODE4, 256, 0, stream>>>(cur, out);
}